// Round 2
// baseline (807.029 us; speedup 1.0000x reference)
//
#include <hip/hip_runtime.h>
#include <hip/hip_fp16.h>
#include <math.h>

// DEG_COUNTS = [20000, 80000, 150000, 150000, 75000, 20000, 5000]
// OFF        = [0, 20000, 100000, 250000, 400000, 475000, 495000, 500000]
// N_ATOMS = 500000, BATCH = 1024, F_IN = 75

struct AdjPtrs { const int* p[6]; };

typedef _Float16 f16x8 __attribute__((ext_vector_type(8)));
typedef float f32x4 __attribute__((ext_vector_type(4)));

__device__ __forceinline__ float tanh_fast(float x) {
  float ax = fabsf(x);
  float r = __expf(-2.f * ax);             // r in (0,1], never inf
  float t = 1.f - 2.f * r * __builtin_amdgcn_rcpf(1.f + r);
  return copysignf(t, x);
}

__device__ __forceinline__ f16x8 max8(f16x8 a, f16x8 b) {
  #pragma unroll
  for (int i = 0; i < 8; i++) a[i] = (a[i] > b[i]) ? a[i] : b[i];  // -> v_pk_max_f16
  return a;
}

// ---------------- membership counting sort ----------------
__global__ __launch_bounds__(256) void k_zero_hist(int* __restrict__ hist) {
  int i = blockIdx.x * 256 + threadIdx.x;
  if (i < 1024) hist[i] = 0;
}

__global__ __launch_bounds__(256) void k_hist(const int* __restrict__ mem, int* __restrict__ hist) {
  __shared__ int lh[1024];
  int tid = threadIdx.x;
  for (int i = tid; i < 1024; i += 256) lh[i] = 0;
  __syncthreads();
  int stride = gridDim.x * 256;
  for (int i = blockIdx.x * 256 + tid; i < 500000; i += stride)
    atomicAdd(&lh[mem[i]], 1);
  __syncthreads();
  for (int i = tid; i < 1024; i += 256) {
    int v = lh[i];
    if (v) atomicAdd(&hist[i], v);
  }
}

__global__ __launch_bounds__(1024) void k_scan(const int* __restrict__ hist,
                                               int* __restrict__ start,
                                               int* __restrict__ cursor) {
  __shared__ int sc[1024];
  int t = threadIdx.x;
  int h = hist[t];
  sc[t] = h;
  __syncthreads();
  for (int off = 1; off < 1024; off <<= 1) {
    int v = (t >= off) ? sc[t - off] : 0;
    __syncthreads();
    sc[t] += v;
    __syncthreads();
  }
  int ex = sc[t] - h;
  start[t] = ex;
  cursor[t] = ex;
}

__global__ __launch_bounds__(256) void k_scatter(const int* __restrict__ mem,
                                                 int* __restrict__ cursor,
                                                 int* __restrict__ list) {
  int i = blockIdx.x * 256 + threadIdx.x;
  if (i < 500000) {
    int pos = atomicAdd(&cursor[mem[i]], 1);
    list[pos] = i;
  }
}

// ---------------- prep: feat fp32[500k x 75] -> fp16 padded [500k x 80] ----------------
__global__ __launch_bounds__(256) void k_prep(const float* __restrict__ feat,
                                              __half2* __restrict__ featH2) {
  int i = blockIdx.x * 256 + threadIdx.x;  // 20,000,000 exactly
  int a = i / 40;
  int jp = i - a * 40;
  int kk = jp * 2;
  float v0 = (kk < 75) ? feat[(size_t)a * 75 + kk] : 0.f;
  float v1 = (kk + 1 < 75) ? feat[(size_t)a * 75 + kk + 1] : 0.f;
  featH2[i] = __floats2half2_rn(v0, v1);
}

// ---------------- prep: W -> fp16 in MFMA B-fragment order ----------------
// Layout per layer: [d][c][ns][lane][j=0..7] where the element is
// B[n][k] = W[k][n], n = ns*16 + (lane&15), k = c*32 + (lane>>4)*8 + j.
__global__ __launch_bounds__(256) void k_prep_w(
    const float* __restrict__ Ws1, const float* __restrict__ Wn1,
    const float* __restrict__ Ws2, const float* __restrict__ Wn2,
    __half* __restrict__ W1H, __half* __restrict__ W2H) {
  int i = blockIdx.x * 256 + threadIdx.x;  // 129024 exactly
  if (i < 71680) {  // layer1: 7 * (5*4*64*8) = 7*10240, KP=160
    int d = i / 10240, r = i - d * 10240;
    int j = r & 7, lane = (r >> 3) & 63, t = r >> 9;  // t = c*4+ns, 0..19
    int n = (t & 3) * 16 + (lane & 15);
    int k = (t >> 2) * 32 + (lane >> 4) * 8 + j;
    float v = 0.f;
    if (k < 75) v = Ws1[d * 4800 + k * 64 + n];
    else if (k >= 80 && k < 155 && d > 0) v = Wn1[(d - 1) * 4800 + (k - 80) * 64 + n];
    W1H[i] = __float2half(v);
  } else {  // layer2: 7 * (4*4*64*8) = 7*8192, KP=128
    int i2 = i - 71680;
    int d = i2 / 8192, r = i2 - d * 8192;
    int j = r & 7, lane = (r >> 3) & 63, t = r >> 9;  // 0..15
    int n = (t & 3) * 16 + (lane & 15);
    int k = (t >> 2) * 32 + (lane >> 4) * 8 + j;
    float v = 0.f;
    if (k < 64) v = Ws2[d * 4096 + k * 64 + n];
    else if (d > 0) v = Wn2[(d - 1) * 4096 + (k - 64) * 64 + n];
    W2H[i2] = __float2half(v);
  }
}

// ---------------- prep: d1_W (64x128 fp32) -> hi/lo fp16 [2][128][64] ----------------
__global__ __launch_bounds__(256) void k_prep_d1(const float* __restrict__ W,
                                                 __half* __restrict__ D1H) {
  int i = blockIdx.x * 256 + threadIdx.x;  // 8192 exactly
  int n = i >> 6, k = i & 63;
  float v = W[k * 128 + n];
  __half hi = __float2half(v);
  D1H[i] = hi;
  D1H[8192 + i] = __float2half(v - __half2float(hi));
}

// ---------------- fused graph_conv (MFMA) + tanh + bn1, fp16 in/out ----------------
// Register-direct A fragments, split into TWO sequential 32-atom passes per wave:
// halves the accumulator (acc[2][4] = 32 regs) and adjacency registers so 4+
// waves/SIMD fit, trading cheap duplicate L1-hot B-fragment loads for occupancy.
template<int FP, int NCH, int D>
__device__ __forceinline__ void gcm_run(
    const __half* __restrict__ featH, const int* __restrict__ adj_g,
    int abase, int na, const f16x8* __restrict__ Wf,
    const float* __restrict__ bias_d,
    const float* __restrict__ bng, const float* __restrict__ bnb,
    const float* __restrict__ bnm, const float* __restrict__ bnv,
    __half* __restrict__ out) {
  int tid = threadIdx.x;
  int lane = tid & 63, w = tid >> 6;
  int ln = lane & 15, q = lane >> 4;

  float sc[4], sh[4], bj[4];
  #pragma unroll
  for (int ns = 0; ns < 4; ns++) {
    int j = ns * 16 + ln;
    sc[ns] = bng[j] * rsqrtf(bnv[j] + 1e-3f);
    sh[ns] = bnb[j] - bnm[j] * sc[ns];
    bj[ns] = bias_d[j];
  }

  #pragma unroll 1   // keep the two halves SEQUENTIAL: this is the register saver
  for (int h = 0; h < 2; h++) {
    // adjacency rows for this half's 2 fragment rows, clamped for the tail
    int ar[2][D > 0 ? D : 1];
    if (D > 0) {
      #pragma unroll
      for (int ms = 0; ms < 2; ms++) {
        int m = w * 64 + (h * 2 + ms) * 16 + ln;
        bool ok = (m < na);
        #pragma unroll
        for (int e = 0; e < D; e++)
          ar[ms][e] = ok ? adj_g[m * D + e] : 0;
      }
    }

    f32x4 acc[2][4];
    #pragma unroll
    for (int ms = 0; ms < 2; ms++)
      #pragma unroll
      for (int ns = 0; ns < 4; ns++)
        acc[ms][ns] = (f32x4){bj[ns], bj[ns], bj[ns], bj[ns]};

    #pragma unroll
    for (int c = 0; c < NCH; c++) {
      int ksg = c * 32 + q * 8;
      f16x8 af[2];
      #pragma unroll
      for (int ms = 0; ms < 2; ms++) {
        int m = w * 64 + (h * 2 + ms) * 16 + ln;
        if (ksg < FP) {
          af[ms] = *(const f16x8*)(featH + (size_t)(abase + m) * FP + ksg);
        } else if (D > 0) {
          int kb = ksg - FP;
          f16x8 v = *(const f16x8*)(featH + (size_t)ar[ms][0] * FP + kb);
          #pragma unroll
          for (int e = 1; e < D; e++) {
            f16x8 u = *(const f16x8*)(featH + (size_t)ar[ms][e] * FP + kb);
            v = v + u;
          }
          af[ms] = v;
        } else {
          af[ms] = (f16x8){};
        }
      }
      f16x8 bf[4];
      #pragma unroll
      for (int ns = 0; ns < 4; ns++)
        bf[ns] = Wf[(c * 4 + ns) * 64 + lane];
      #pragma unroll
      for (int ms = 0; ms < 2; ms++)
        #pragma unroll
        for (int ns = 0; ns < 4; ns++)
          acc[ms][ns] = __builtin_amdgcn_mfma_f32_16x16x32_f16(af[ms], bf[ns], acc[ms][ns], 0, 0, 0);
    }

    // epilogue for this half: tanh + bn, store fp16.
    // D layout: col=lane&15, row=(lane>>4)*4+reg
    #pragma unroll
    for (int ms = 0; ms < 2; ms++) {
      #pragma unroll
      for (int ns = 0; ns < 4; ns++) {
        int j = ns * 16 + ln;
        #pragma unroll
        for (int r = 0; r < 4; r++) {
          int atom = w * 64 + (h * 2 + ms) * 16 + q * 4 + r;
          if (atom < na)
            out[(size_t)(abase + atom) * 64 + j] =
                __float2half(tanh_fast(acc[ms][ns][r]) * sc[ns] + sh[ns]);
        }
      }
    }
  }
}

template<int FP, int NCH>
__global__ __launch_bounds__(256, 4) void k_gcm(
    const __half* __restrict__ featH, AdjPtrs adjs,
    const __half* __restrict__ WtH, const float* __restrict__ bias,
    const float* __restrict__ bng, const float* __restrict__ bnb,
    const float* __restrict__ bnm, const float* __restrict__ bnv,
    __half* __restrict__ out) {
  int bid = blockIdx.x;
  int d, off, end, bloc;
  if      (bid < 79)   { d = 0; bloc = bid;        off = 0;      end = 20000;  }
  else if (bid < 392)  { d = 1; bloc = bid - 79;   off = 20000;  end = 100000; }
  else if (bid < 978)  { d = 2; bloc = bid - 392;  off = 100000; end = 250000; }
  else if (bid < 1564) { d = 3; bloc = bid - 978;  off = 250000; end = 400000; }
  else if (bid < 1857) { d = 4; bloc = bid - 1564; off = 400000; end = 475000; }
  else if (bid < 1936) { d = 5; bloc = bid - 1857; off = 475000; end = 495000; }
  else                 { d = 6; bloc = bid - 1936; off = 495000; end = 500000; }
  int abase = off + bloc * 256;
  int na = min(256, end - abase);
  const int* adj_g = (d > 0) ? adjs.p[d - 1] + (abase - off) * d : (const int*)0;
  const f16x8* Wf = (const f16x8*)WtH + d * (NCH * 4 * 64);
  const float* bias_d = bias + d * 64;

  switch (d) {
    case 0: gcm_run<FP, NCH, 0>(featH, adj_g, abase, na, Wf, bias_d, bng, bnb, bnm, bnv, out); break;
    case 1: gcm_run<FP, NCH, 1>(featH, adj_g, abase, na, Wf, bias_d, bng, bnb, bnm, bnv, out); break;
    case 2: gcm_run<FP, NCH, 2>(featH, adj_g, abase, na, Wf, bias_d, bng, bnb, bnm, bnv, out); break;
    case 3: gcm_run<FP, NCH, 3>(featH, adj_g, abase, na, Wf, bias_d, bng, bnb, bnm, bnv, out); break;
    case 4: gcm_run<FP, NCH, 4>(featH, adj_g, abase, na, Wf, bias_d, bng, bnb, bnm, bnv, out); break;
    case 5: gcm_run<FP, NCH, 5>(featH, adj_g, abase, na, Wf, bias_d, bng, bnb, bnm, bnv, out); break;
    default: gcm_run<FP, NCH, 6>(featH, adj_g, abase, na, Wf, bias_d, bng, bnb, bnm, bnv, out); break;
  }
}

// ---------------- graph_pool fp16, 16B segments + packed max ----------------
template<int D>
__device__ __forceinline__ f16x8 pool_h_acc(const f16x8* __restrict__ in8,
                                            const int* __restrict__ ad, int sg, f16x8 v) {
  #pragma unroll
  for (int e = 0; e < D; e++) v = max8(v, in8[ad[e] * 8 + sg]);
  return v;
}

__global__ __launch_bounds__(256) void k_pool_h(const f16x8* __restrict__ in8, AdjPtrs adjs,
                                                f16x8* __restrict__ out8) {
  int t = blockIdx.x * 256 + threadIdx.x;  // 4,000,000 exactly
  int atom = t >> 3, sg = t & 7;
  int d, off;
  if      (atom < 20000)  { d = 0; off = 0;      }
  else if (atom < 100000) { d = 1; off = 20000;  }
  else if (atom < 250000) { d = 2; off = 100000; }
  else if (atom < 400000) { d = 3; off = 250000; }
  else if (atom < 475000) { d = 4; off = 400000; }
  else if (atom < 495000) { d = 5; off = 475000; }
  else                    { d = 6; off = 495000; }
  f16x8 v = in8[atom * 8 + sg];
  if (d > 0) {
    const int* ad = adjs.p[d - 1] + (atom - off) * d;
    switch (d) {
      case 1: v = pool_h_acc<1>(in8, ad, sg, v); break;
      case 2: v = pool_h_acc<2>(in8, ad, sg, v); break;
      case 3: v = pool_h_acc<3>(in8, ad, sg, v); break;
      case 4: v = pool_h_acc<4>(in8, ad, sg, v); break;
      case 5: v = pool_h_acc<5>(in8, ad, sg, v); break;
      default: v = pool_h_acc<6>(in8, ad, sg, v); break;
    }
  }
  out8[atom * 8 + sg] = v;
}

// ---------------- fused dense1(MFMA, hi/lo W) + tanh + bn3 + segment sum/max + tanh ----
__global__ __launch_bounds__(256, 3) void k_dense1f(
    const __half2* __restrict__ hD2, const int* __restrict__ list,
    const int* __restrict__ start, const int* __restrict__ hist,
    const __half* __restrict__ D1H, const float* __restrict__ d1b,
    const float* __restrict__ g3, const float* __restrict__ b3,
    const float* __restrict__ m3, const float* __restrict__ v3,
    float* __restrict__ g) {
  __shared__ __align__(16) __half Bt[2][128 * 72];
  __shared__ __align__(16) __half Ac[64 * 72];
  int b = blockIdx.x, tid = threadIdx.x;
  int stt = start[b], cnt = hist[b];

  for (int i = tid; i < 8192; i += 256) {
    int n = i >> 6, k = i & 63;
    Bt[0][n * 72 + k] = D1H[i];
    Bt[1][n * 72 + k] = D1H[8192 + i];
  }

  int lane = tid & 63, w = tid >> 6;
  int ln = lane & 15, q = lane >> 4;

  float bj[2], sc[2], sh[2];
  #pragma unroll
  for (int nf = 0; nf < 2; nf++) {
    int col = w * 32 + nf * 16 + ln;
    bj[nf] = d1b[col];
    sc[nf] = g3[col] * rsqrtf(v3[col] + 1e-3f);
    sh[nf] = b3[col] - m3[col] * sc[nf];
  }

  float sum[2] = {0.f, 0.f};
  float mx[2] = {-INFINITY, -INFINITY};

  for (int cb = 0; cb < cnt; cb += 64) {
    int nr = min(64, cnt - cb);
    __syncthreads();  // covers W staging (1st iter) + prior Ac readers
    {
      int r = tid >> 2;
      #pragma unroll
      for (int it = 0; it < 2; it++) {
        int sg = (tid & 3) + it * 4;  // 8-half (16 B) segment
        __half2* dst = (__half2*)(Ac + r * 72 + sg * 8);
        if (r < nr) {
          int a = list[stt + cb + r];
          const __half2* src = hD2 + (size_t)a * 32 + sg * 4;
          __half2 v0 = src[0], v1 = src[1], v2 = src[2], v3h = src[3];
          dst[0] = v0; dst[1] = v1; dst[2] = v2; dst[3] = v3h;
        } else {
          __half2 z = __floats2half2_rn(0.f, 0.f);
          dst[0] = z; dst[1] = z; dst[2] = z; dst[3] = z;
        }
      }
    }
    __syncthreads();

    f32x4 acc[4][2];
    #pragma unroll
    for (int mf = 0; mf < 4; mf++)
      #pragma unroll
      for (int nf = 0; nf < 2; nf++) acc[mf][nf] = (f32x4){bj[nf], bj[nf], bj[nf], bj[nf]};

    #pragma unroll
    for (int hl = 1; hl >= 0; hl--) {
      #pragma unroll
      for (int ks = 0; ks < 2; ks++) {
        f16x8 af[4], bf[2];
        #pragma unroll
        for (int mf = 0; mf < 4; mf++)
          af[mf] = *(const f16x8*)(Ac + (mf * 16 + ln) * 72 + ks * 32 + q * 8);
        #pragma unroll
        for (int nf = 0; nf < 2; nf++)
          bf[nf] = *(const f16x8*)(&Bt[hl][(w * 32 + nf * 16 + ln) * 72 + ks * 32 + q * 8]);
        #pragma unroll
        for (int mf = 0; mf < 4; mf++)
          #pragma unroll
          for (int nf = 0; nf < 2; nf++)
            acc[mf][nf] = __builtin_amdgcn_mfma_f32_16x16x32_f16(af[mf], bf[nf], acc[mf][nf], 0, 0, 0);
      }
    }

    #pragma unroll
    for (int mf = 0; mf < 4; mf++) {
      #pragma unroll
      for (int nf = 0; nf < 2; nf++) {
        #pragma unroll
        for (int r = 0; r < 4; r++) {
          int row = mf * 16 + q * 4 + r;
          if (row < nr) {
            float v = tanh_fast(acc[mf][nf][r]) * sc[nf] + sh[nf];
            sum[nf] += v;
            mx[nf] = fmaxf(mx[nf], v);
          }
        }
      }
    }
  }

  #pragma unroll
  for (int nf = 0; nf < 2; nf++) {
    sum[nf] += __shfl_xor(sum[nf], 16);
    sum[nf] += __shfl_xor(sum[nf], 32);
    mx[nf] = fmaxf(mx[nf], __shfl_xor(mx[nf], 16));
    mx[nf] = fmaxf(mx[nf], __shfl_xor(mx[nf], 32));
  }
  if (q == 0) {
    #pragma unroll
    for (int nf = 0; nf < 2; nf++) {
      int col = w * 32 + nf * 16 + ln;
      g[b * 256 + col] = tanh_fast(sum[nf]);
      g[b * 256 + 128 + col] = tanh_fast(mx[nf]);
    }
  }
}

// ---------------- dense2 -> sigmoid -> dense3 ----------------
__global__ __launch_bounds__(64) void k_dense23(
    const float* __restrict__ g, const float* __restrict__ W2,
    const float* __restrict__ b2, const float* __restrict__ W3,
    const float* __restrict__ b3, float* __restrict__ out) {
  __shared__ float gr[256];
  int b = blockIdx.x, j = threadIdx.x;
  ((float4*)gr)[j] = ((const float4*)(g + b * 256))[j];
  __syncthreads();
  float acc = b2[j];
  #pragma unroll 8
  for (int k = 0; k < 256; k++) acc += gr[k] * W2[k * 64 + j];
  float sg = 1.f / (1.f + expf(-acc));
  float p = sg * W3[j];
  #pragma unroll
  for (int off = 32; off >= 1; off >>= 1) p += __shfl_xor(p, off);
  if (j == 0) out[b] = p + b3[0];
}

// ---------------- launch ----------------
extern "C" void kernel_launch(void* const* d_in, const int* in_sizes, int n_in,
                              void* d_out, int out_size, void* d_ws, size_t ws_size,
                              hipStream_t stream) {
  const float* feat = (const float*)d_in[0];
  const int*   mem  = (const int*)d_in[1];
  AdjPtrs adjs;
  for (int i = 0; i < 6; i++) adjs.p[i] = (const int*)d_in[2 + i];
  const float* gc1_Wn = (const float*)d_in[8];
  const float* gc1_Ws = (const float*)d_in[9];
  const float* gc1_b  = (const float*)d_in[10];
  const float* gc2_Wn = (const float*)d_in[11];
  const float* gc2_Ws = (const float*)d_in[12];
  const float* gc2_b  = (const float*)d_in[13];
  const float* bn1g = (const float*)d_in[14];
  const float* bn1b = (const float*)d_in[15];
  const float* bn1m = (const float*)d_in[16];
  const float* bn1v = (const float*)d_in[17];
  const float* bn3g = (const float*)d_in[18];
  const float* bn3b = (const float*)d_in[19];
  const float* bn3m = (const float*)d_in[20];
  const float* bn3v = (const float*)d_in[21];
  const float* d1W = (const float*)d_in[22];
  const float* d1b = (const float*)d_in[23];
  const float* d2W = (const float*)d_in[24];
  const float* d2b = (const float*)d_in[25];
  const float* d3W = (const float*)d_in[26];
  const float* d3b = (const float*)d_in[27];
  float* out = (float*)d_out;

  char* w = (char*)d_ws;
  __half* featH = (__half*)(w);
  __half* hA    = (__half*)(w + 80000000LL);
  __half* hB    = (__half*)(w + 144000000LL);
  __half* hC    = (__half*)(w);              // gc2 out (featH dead)
  __half* hD    = (__half*)(w + 80000000LL); // pool2 out (hA dead)
  __half* W1H   = (__half*)(w + 210000000LL);
  __half* W2H   = (__half*)(w + 210200000LL);
  __half* D1H   = (__half*)(w + 210330000LL);  // 32 KB hi/lo
  float*  g     = (float*)(w + 210400000LL);   // 1 MB
  int* hist     = (int*)(w + 211600000LL);
  int* start    = (int*)(w + 211604096LL);
  int* cursor   = (int*)(w + 211608192LL);
  int* list     = (int*)(w + 211612288LL);     // 2 MB

  // membership counting sort
  k_zero_hist<<<4, 256, 0, stream>>>(hist);
  k_hist<<<512, 256, 0, stream>>>(mem, hist);
  k_scan<<<1, 1024, 0, stream>>>(hist, start, cursor);
  k_scatter<<<1954, 256, 0, stream>>>(mem, cursor, list);

  // prep
  k_prep<<<78125, 256, 0, stream>>>(feat, (__half2*)featH);
  k_prep_w<<<504, 256, 0, stream>>>(gc1_Ws, gc1_Wn, gc2_Ws, gc2_Wn, W1H, W2H);
  k_prep_d1<<<32, 256, 0, stream>>>(d1W, D1H);

  // main pipeline
  k_gcm<80, 5><<<1956, 256, 0, stream>>>(featH, adjs, W1H, gc1_b,
                                         bn1g, bn1b, bn1m, bn1v, hA);
  k_pool_h<<<15625, 256, 0, stream>>>((const f16x8*)hA, adjs, (f16x8*)hB);
  k_gcm<64, 4><<<1956, 256, 0, stream>>>(hB, adjs, W2H, gc2_b,
                                         bn1g, bn1b, bn1m, bn1v, hC);
  k_pool_h<<<15625, 256, 0, stream>>>((const f16x8*)hC, adjs, (f16x8*)hD);
  k_dense1f<<<1024, 256, 0, stream>>>((const __half2*)hD, list, start, hist, D1H, d1b,
                                      bn3g, bn3b, bn3m, bn3v, g);
  k_dense23<<<1024, 64, 0, stream>>>(g, d2W, d2b, d3W, d3b, out);
}

// Round 3
// 707.617 us; speedup vs baseline: 1.1405x; 1.1405x over previous
//
#include <hip/hip_runtime.h>
#include <hip/hip_fp16.h>
#include <math.h>

// DEG_COUNTS = [20000, 80000, 150000, 150000, 75000, 20000, 5000]
// OFF        = [0, 20000, 100000, 250000, 400000, 475000, 495000, 500000]
// N_ATOMS = 500000, BATCH = 1024, F_IN = 75

struct AdjPtrs { const int* p[6]; };

typedef _Float16 f16x8 __attribute__((ext_vector_type(8)));
typedef float f32x4 __attribute__((ext_vector_type(4)));

__device__ __forceinline__ float tanh_fast(float x) {
  float ax = fabsf(x);
  float r = __expf(-2.f * ax);             // r in (0,1], never inf
  float t = 1.f - 2.f * r * __builtin_amdgcn_rcpf(1.f + r);
  return copysignf(t, x);
}

__device__ __forceinline__ f16x8 max8(f16x8 a, f16x8 b) {
  #pragma unroll
  for (int i = 0; i < 8; i++) a[i] = (a[i] > b[i]) ? a[i] : b[i];  // -> v_pk_max_f16
  return a;
}

// ---------------- membership counting sort ----------------
__global__ __launch_bounds__(256) void k_zero_hist(int* __restrict__ hist) {
  int i = blockIdx.x * 256 + threadIdx.x;
  if (i < 1024) hist[i] = 0;
}

__global__ __launch_bounds__(256) void k_hist(const int* __restrict__ mem, int* __restrict__ hist) {
  __shared__ int lh[1024];
  int tid = threadIdx.x;
  for (int i = tid; i < 1024; i += 256) lh[i] = 0;
  __syncthreads();
  int stride = gridDim.x * 256;
  for (int i = blockIdx.x * 256 + tid; i < 500000; i += stride)
    atomicAdd(&lh[mem[i]], 1);
  __syncthreads();
  for (int i = tid; i < 1024; i += 256) {
    int v = lh[i];
    if (v) atomicAdd(&hist[i], v);
  }
}

__global__ __launch_bounds__(1024) void k_scan(const int* __restrict__ hist,
                                               int* __restrict__ start,
                                               int* __restrict__ cursor) {
  __shared__ int sc[1024];
  int t = threadIdx.x;
  int h = hist[t];
  sc[t] = h;
  __syncthreads();
  for (int off = 1; off < 1024; off <<= 1) {
    int v = (t >= off) ? sc[t - off] : 0;
    __syncthreads();
    sc[t] += v;
    __syncthreads();
  }
  int ex = sc[t] - h;
  start[t] = ex;
  cursor[t] = ex;
}

__global__ __launch_bounds__(256) void k_scatter(const int* __restrict__ mem,
                                                 int* __restrict__ cursor,
                                                 int* __restrict__ list) {
  int i = blockIdx.x * 256 + threadIdx.x;
  if (i < 500000) {
    int pos = atomicAdd(&cursor[mem[i]], 1);
    list[pos] = i;
  }
}

// ---------------- prep: feat fp32[500k x 75] -> fp16 padded [500k x 80] ----------------
__global__ __launch_bounds__(256) void k_prep(const float* __restrict__ feat,
                                              __half2* __restrict__ featH2) {
  int i = blockIdx.x * 256 + threadIdx.x;  // 20,000,000 exactly
  int a = i / 40;
  int jp = i - a * 40;
  int kk = jp * 2;
  float v0 = (kk < 75) ? feat[(size_t)a * 75 + kk] : 0.f;
  float v1 = (kk + 1 < 75) ? feat[(size_t)a * 75 + kk + 1] : 0.f;
  featH2[i] = __floats2half2_rn(v0, v1);
}

// ---------------- prep: W -> fp16 in MFMA B-fragment order ----------------
// Layout per layer: [d][c][ns][lane][j=0..7] where the element is
// B[n][k] = W[k][n], n = ns*16 + (lane&15), k = c*32 + (lane>>4)*8 + j.
__global__ __launch_bounds__(256) void k_prep_w(
    const float* __restrict__ Ws1, const float* __restrict__ Wn1,
    const float* __restrict__ Ws2, const float* __restrict__ Wn2,
    __half* __restrict__ W1H, __half* __restrict__ W2H) {
  int i = blockIdx.x * 256 + threadIdx.x;  // 129024 exactly
  if (i < 71680) {  // layer1: 7 * (5*4*64*8) = 7*10240, KP=160
    int d = i / 10240, r = i - d * 10240;
    int j = r & 7, lane = (r >> 3) & 63, t = r >> 9;  // t = c*4+ns, 0..19
    int n = (t & 3) * 16 + (lane & 15);
    int k = (t >> 2) * 32 + (lane >> 4) * 8 + j;
    float v = 0.f;
    if (k < 75) v = Ws1[d * 4800 + k * 64 + n];
    else if (k >= 80 && k < 155 && d > 0) v = Wn1[(d - 1) * 4800 + (k - 80) * 64 + n];
    W1H[i] = __float2half(v);
  } else {  // layer2: 7 * (4*4*64*8) = 7*8192, KP=128
    int i2 = i - 71680;
    int d = i2 / 8192, r = i2 - d * 8192;
    int j = r & 7, lane = (r >> 3) & 63, t = r >> 9;  // 0..15
    int n = (t & 3) * 16 + (lane & 15);
    int k = (t >> 2) * 32 + (lane >> 4) * 8 + j;
    float v = 0.f;
    if (k < 64) v = Ws2[d * 4096 + k * 64 + n];
    else if (d > 0) v = Wn2[(d - 1) * 4096 + (k - 64) * 64 + n];
    W2H[i2] = __float2half(v);
  }
}

// ---------------- prep: d1_W (64x128 fp32) -> hi/lo fp16 [2][128][64] ----------------
__global__ __launch_bounds__(256) void k_prep_d1(const float* __restrict__ W,
                                                 __half* __restrict__ D1H) {
  int i = blockIdx.x * 256 + threadIdx.x;  // 8192 exactly
  int n = i >> 6, k = i & 63;
  float v = W[k * 128 + n];
  __half hi = __float2half(v);
  D1H[i] = hi;
  D1H[8192 + i] = __float2half(v - __half2float(hi));
}

// ---------------- fused graph_conv (MFMA) + tanh + bn1, fp16 in/out ----------------
// Each wave owns 32 atoms (acc[2][4] = 32 AGPR). Register-direct A gathers from
// global, no LDS/barriers. Bias folded into acc init; bn scale/shift recomputed
// in the epilogue so the c-loop live set stays < 64 VGPR -> 4 waves/SIMD, no spill.
template<int FP, int NCH, int D>
__device__ __forceinline__ void gcm_run(
    const __half* __restrict__ featH, const int* __restrict__ adj_g,
    int abase, int na, const f16x8* __restrict__ Wf,
    const float* __restrict__ bias_d,
    const float* __restrict__ bng, const float* __restrict__ bnb,
    const float* __restrict__ bnm, const float* __restrict__ bnv,
    __half* __restrict__ out) {
  int tid = threadIdx.x;
  int lane = tid & 63, w = tid >> 6;
  int ln = lane & 15, q = lane >> 4;

  // adjacency rows for this wave's 2 fragment rows, clamped for the tail
  int ar[2][D > 0 ? D : 1];
  if (D > 0) {
    #pragma unroll
    for (int ms = 0; ms < 2; ms++) {
      int m = w * 32 + ms * 16 + ln;
      bool ok = (m < na);
      #pragma unroll
      for (int e = 0; e < D; e++)
        ar[ms][e] = ok ? adj_g[m * D + e] : 0;
    }
  }

  f32x4 acc[2][4];
  #pragma unroll
  for (int ns = 0; ns < 4; ns++) {
    float bj = bias_d[ns * 16 + ln];
    acc[0][ns] = (f32x4){bj, bj, bj, bj};
    acc[1][ns] = acc[0][ns];
  }

  #pragma unroll
  for (int c = 0; c < NCH; c++) {
    int ksg = c * 32 + q * 8;
    f16x8 af[2];
    #pragma unroll
    for (int ms = 0; ms < 2; ms++) {
      int m = w * 32 + ms * 16 + ln;
      if (ksg < FP) {
        af[ms] = *(const f16x8*)(featH + (size_t)(abase + m) * FP + ksg);
      } else if (D > 0) {
        int kb = ksg - FP;
        f16x8 v = *(const f16x8*)(featH + (size_t)ar[ms][0] * FP + kb);
        #pragma unroll
        for (int e = 1; e < D; e++) {
          f16x8 u = *(const f16x8*)(featH + (size_t)ar[ms][e] * FP + kb);
          v = v + u;
        }
        af[ms] = v;
      } else {
        af[ms] = (f16x8){};
      }
    }
    #pragma unroll
    for (int ns = 0; ns < 4; ns++) {
      f16x8 bf = Wf[(c * 4 + ns) * 64 + lane];
      acc[0][ns] = __builtin_amdgcn_mfma_f32_16x16x32_f16(af[0], bf, acc[0][ns], 0, 0, 0);
      acc[1][ns] = __builtin_amdgcn_mfma_f32_16x16x32_f16(af[1], bf, acc[1][ns], 0, 0, 0);
    }
  }

  // epilogue: tanh + bn, store fp16. D layout: col=lane&15, row=(lane>>4)*4+reg
  #pragma unroll
  for (int ns = 0; ns < 4; ns++) {
    int j = ns * 16 + ln;
    float scv = bng[j] * rsqrtf(bnv[j] + 1e-3f);
    float shv = bnb[j] - bnm[j] * scv;
    #pragma unroll
    for (int ms = 0; ms < 2; ms++) {
      #pragma unroll
      for (int r = 0; r < 4; r++) {
        int atom = w * 32 + ms * 16 + q * 4 + r;
        if (atom < na)
          out[(size_t)(abase + atom) * 64 + j] =
              __float2half(tanh_fast(acc[ms][ns][r]) * scv + shv);
      }
    }
  }
}

template<int FP, int NCH>
__global__ __launch_bounds__(256, 4) void k_gcm(
    const __half* __restrict__ featH, AdjPtrs adjs,
    const __half* __restrict__ WtH, const float* __restrict__ bias,
    const float* __restrict__ bng, const float* __restrict__ bnb,
    const float* __restrict__ bnm, const float* __restrict__ bnv,
    __half* __restrict__ out) {
  int bid = blockIdx.x;  // 3909 blocks of 128 atoms
  int d, off, end, bloc;
  if      (bid < 157)  { d = 0; bloc = bid;        off = 0;      end = 20000;  }
  else if (bid < 782)  { d = 1; bloc = bid - 157;  off = 20000;  end = 100000; }
  else if (bid < 1954) { d = 2; bloc = bid - 782;  off = 100000; end = 250000; }
  else if (bid < 3126) { d = 3; bloc = bid - 1954; off = 250000; end = 400000; }
  else if (bid < 3712) { d = 4; bloc = bid - 3126; off = 400000; end = 475000; }
  else if (bid < 3869) { d = 5; bloc = bid - 3712; off = 475000; end = 495000; }
  else                 { d = 6; bloc = bid - 3869; off = 495000; end = 500000; }
  int abase = off + bloc * 128;
  int na = min(128, end - abase);
  const int* adj_g = (d > 0) ? adjs.p[d - 1] + (abase - off) * d : (const int*)0;
  const f16x8* Wf = (const f16x8*)WtH + d * (NCH * 4 * 64);
  const float* bias_d = bias + d * 64;

  switch (d) {
    case 0: gcm_run<FP, NCH, 0>(featH, adj_g, abase, na, Wf, bias_d, bng, bnb, bnm, bnv, out); break;
    case 1: gcm_run<FP, NCH, 1>(featH, adj_g, abase, na, Wf, bias_d, bng, bnb, bnm, bnv, out); break;
    case 2: gcm_run<FP, NCH, 2>(featH, adj_g, abase, na, Wf, bias_d, bng, bnb, bnm, bnv, out); break;
    case 3: gcm_run<FP, NCH, 3>(featH, adj_g, abase, na, Wf, bias_d, bng, bnb, bnm, bnv, out); break;
    case 4: gcm_run<FP, NCH, 4>(featH, adj_g, abase, na, Wf, bias_d, bng, bnb, bnm, bnv, out); break;
    case 5: gcm_run<FP, NCH, 5>(featH, adj_g, abase, na, Wf, bias_d, bng, bnb, bnm, bnv, out); break;
    default: gcm_run<FP, NCH, 6>(featH, adj_g, abase, na, Wf, bias_d, bng, bnb, bnm, bnv, out); break;
  }
}

// ---------------- graph_pool fp16, 16B segments + packed max ----------------
template<int D>
__device__ __forceinline__ f16x8 pool_h_acc(const f16x8* __restrict__ in8,
                                            const int* __restrict__ ad, int sg, f16x8 v) {
  #pragma unroll
  for (int e = 0; e < D; e++) v = max8(v, in8[ad[e] * 8 + sg]);
  return v;
}

__global__ __launch_bounds__(256) void k_pool_h(const f16x8* __restrict__ in8, AdjPtrs adjs,
                                                f16x8* __restrict__ out8) {
  int t = blockIdx.x * 256 + threadIdx.x;  // 4,000,000 exactly
  int atom = t >> 3, sg = t & 7;
  int d, off;
  if      (atom < 20000)  { d = 0; off = 0;      }
  else if (atom < 100000) { d = 1; off = 20000;  }
  else if (atom < 250000) { d = 2; off = 100000; }
  else if (atom < 400000) { d = 3; off = 250000; }
  else if (atom < 475000) { d = 4; off = 400000; }
  else if (atom < 495000) { d = 5; off = 475000; }
  else                    { d = 6; off = 495000; }
  f16x8 v = in8[atom * 8 + sg];
  if (d > 0) {
    const int* ad = adjs.p[d - 1] + (atom - off) * d;
    switch (d) {
      case 1: v = pool_h_acc<1>(in8, ad, sg, v); break;
      case 2: v = pool_h_acc<2>(in8, ad, sg, v); break;
      case 3: v = pool_h_acc<3>(in8, ad, sg, v); break;
      case 4: v = pool_h_acc<4>(in8, ad, sg, v); break;
      case 5: v = pool_h_acc<5>(in8, ad, sg, v); break;
      default: v = pool_h_acc<6>(in8, ad, sg, v); break;
    }
  }
  out8[atom * 8 + sg] = v;
}

// ---------------- fused dense1(MFMA, hi/lo W) + tanh + bn3 + segment sum/max + tanh ----
__global__ __launch_bounds__(256, 3) void k_dense1f(
    const __half2* __restrict__ hD2, const int* __restrict__ list,
    const int* __restrict__ start, const int* __restrict__ hist,
    const __half* __restrict__ D1H, const float* __restrict__ d1b,
    const float* __restrict__ g3, const float* __restrict__ b3,
    const float* __restrict__ m3, const float* __restrict__ v3,
    float* __restrict__ g) {
  __shared__ __align__(16) __half Bt[2][128 * 72];
  __shared__ __align__(16) __half Ac[64 * 72];
  int b = blockIdx.x, tid = threadIdx.x;
  int stt = start[b], cnt = hist[b];

  for (int i = tid; i < 8192; i += 256) {
    int n = i >> 6, k = i & 63;
    Bt[0][n * 72 + k] = D1H[i];
    Bt[1][n * 72 + k] = D1H[8192 + i];
  }

  int lane = tid & 63, w = tid >> 6;
  int ln = lane & 15, q = lane >> 4;

  float bj[2], sc[2], sh[2];
  #pragma unroll
  for (int nf = 0; nf < 2; nf++) {
    int col = w * 32 + nf * 16 + ln;
    bj[nf] = d1b[col];
    sc[nf] = g3[col] * rsqrtf(v3[col] + 1e-3f);
    sh[nf] = b3[col] - m3[col] * sc[nf];
  }

  float sum[2] = {0.f, 0.f};
  float mx[2] = {-INFINITY, -INFINITY};

  for (int cb = 0; cb < cnt; cb += 64) {
    int nr = min(64, cnt - cb);
    __syncthreads();  // covers W staging (1st iter) + prior Ac readers
    {
      int r = tid >> 2;
      #pragma unroll
      for (int it = 0; it < 2; it++) {
        int sg = (tid & 3) + it * 4;  // 8-half (16 B) segment
        __half2* dst = (__half2*)(Ac + r * 72 + sg * 8);
        if (r < nr) {
          int a = list[stt + cb + r];
          const __half2* src = hD2 + (size_t)a * 32 + sg * 4;
          __half2 v0 = src[0], v1 = src[1], v2 = src[2], v3h = src[3];
          dst[0] = v0; dst[1] = v1; dst[2] = v2; dst[3] = v3h;
        } else {
          __half2 z = __floats2half2_rn(0.f, 0.f);
          dst[0] = z; dst[1] = z; dst[2] = z; dst[3] = z;
        }
      }
    }
    __syncthreads();

    f32x4 acc[4][2];
    #pragma unroll
    for (int mf = 0; mf < 4; mf++)
      #pragma unroll
      for (int nf = 0; nf < 2; nf++) acc[mf][nf] = (f32x4){bj[nf], bj[nf], bj[nf], bj[nf]};

    #pragma unroll
    for (int hl = 1; hl >= 0; hl--) {
      #pragma unroll
      for (int ks = 0; ks < 2; ks++) {
        f16x8 af[4], bf[2];
        #pragma unroll
        for (int mf = 0; mf < 4; mf++)
          af[mf] = *(const f16x8*)(Ac + (mf * 16 + ln) * 72 + ks * 32 + q * 8);
        #pragma unroll
        for (int nf = 0; nf < 2; nf++)
          bf[nf] = *(const f16x8*)(&Bt[hl][(w * 32 + nf * 16 + ln) * 72 + ks * 32 + q * 8]);
        #pragma unroll
        for (int mf = 0; mf < 4; mf++)
          #pragma unroll
          for (int nf = 0; nf < 2; nf++)
            acc[mf][nf] = __builtin_amdgcn_mfma_f32_16x16x32_f16(af[mf], bf[nf], acc[mf][nf], 0, 0, 0);
      }
    }

    #pragma unroll
    for (int mf = 0; mf < 4; mf++) {
      #pragma unroll
      for (int nf = 0; nf < 2; nf++) {
        #pragma unroll
        for (int r = 0; r < 4; r++) {
          int row = mf * 16 + q * 4 + r;
          if (row < nr) {
            float v = tanh_fast(acc[mf][nf][r]) * sc[nf] + sh[nf];
            sum[nf] += v;
            mx[nf] = fmaxf(mx[nf], v);
          }
        }
      }
    }
  }

  #pragma unroll
  for (int nf = 0; nf < 2; nf++) {
    sum[nf] += __shfl_xor(sum[nf], 16);
    sum[nf] += __shfl_xor(sum[nf], 32);
    mx[nf] = fmaxf(mx[nf], __shfl_xor(mx[nf], 16));
    mx[nf] = fmaxf(mx[nf], __shfl_xor(mx[nf], 32));
  }
  if (q == 0) {
    #pragma unroll
    for (int nf = 0; nf < 2; nf++) {
      int col = w * 32 + nf * 16 + ln;
      g[b * 256 + col] = tanh_fast(sum[nf]);
      g[b * 256 + 128 + col] = tanh_fast(mx[nf]);
    }
  }
}

// ---------------- dense2 -> sigmoid -> dense3 ----------------
__global__ __launch_bounds__(64) void k_dense23(
    const float* __restrict__ g, const float* __restrict__ W2,
    const float* __restrict__ b2, const float* __restrict__ W3,
    const float* __restrict__ b3, float* __restrict__ out) {
  __shared__ float gr[256];
  int b = blockIdx.x, j = threadIdx.x;
  ((float4*)gr)[j] = ((const float4*)(g + b * 256))[j];
  __syncthreads();
  float acc = b2[j];
  #pragma unroll 8
  for (int k = 0; k < 256; k++) acc += gr[k] * W2[k * 64 + j];
  float sg = 1.f / (1.f + expf(-acc));
  float p = sg * W3[j];
  #pragma unroll
  for (int off = 32; off >= 1; off >>= 1) p += __shfl_xor(p, off);
  if (j == 0) out[b] = p + b3[0];
}

// ---------------- launch ----------------
extern "C" void kernel_launch(void* const* d_in, const int* in_sizes, int n_in,
                              void* d_out, int out_size, void* d_ws, size_t ws_size,
                              hipStream_t stream) {
  const float* feat = (const float*)d_in[0];
  const int*   mem  = (const int*)d_in[1];
  AdjPtrs adjs;
  for (int i = 0; i < 6; i++) adjs.p[i] = (const int*)d_in[2 + i];
  const float* gc1_Wn = (const float*)d_in[8];
  const float* gc1_Ws = (const float*)d_in[9];
  const float* gc1_b  = (const float*)d_in[10];
  const float* gc2_Wn = (const float*)d_in[11];
  const float* gc2_Ws = (const float*)d_in[12];
  const float* gc2_b  = (const float*)d_in[13];
  const float* bn1g = (const float*)d_in[14];
  const float* bn1b = (const float*)d_in[15];
  const float* bn1m = (const float*)d_in[16];
  const float* bn1v = (const float*)d_in[17];
  const float* bn3g = (const float*)d_in[18];
  const float* bn3b = (const float*)d_in[19];
  const float* bn3m = (const float*)d_in[20];
  const float* bn3v = (const float*)d_in[21];
  const float* d1W = (const float*)d_in[22];
  const float* d1b = (const float*)d_in[23];
  const float* d2W = (const float*)d_in[24];
  const float* d2b = (const float*)d_in[25];
  const float* d3W = (const float*)d_in[26];
  const float* d3b = (const float*)d_in[27];
  float* out = (float*)d_out;

  char* w = (char*)d_ws;
  __half* featH = (__half*)(w);
  __half* hA    = (__half*)(w + 80000000LL);
  __half* hB    = (__half*)(w + 144000000LL);
  __half* hC    = (__half*)(w);              // gc2 out (featH dead)
  __half* hD    = (__half*)(w + 80000000LL); // pool2 out (hA dead)
  __half* W1H   = (__half*)(w + 210000000LL);
  __half* W2H   = (__half*)(w + 210200000LL);
  __half* D1H   = (__half*)(w + 210330000LL);  // 32 KB hi/lo
  float*  g     = (float*)(w + 210400000LL);   // 1 MB
  int* hist     = (int*)(w + 211600000LL);
  int* start    = (int*)(w + 211604096LL);
  int* cursor   = (int*)(w + 211608192LL);
  int* list     = (int*)(w + 211612288LL);     // 2 MB

  // membership counting sort
  k_zero_hist<<<4, 256, 0, stream>>>(hist);
  k_hist<<<512, 256, 0, stream>>>(mem, hist);
  k_scan<<<1, 1024, 0, stream>>>(hist, start, cursor);
  k_scatter<<<1954, 256, 0, stream>>>(mem, cursor, list);

  // prep
  k_prep<<<78125, 256, 0, stream>>>(feat, (__half2*)featH);
  k_prep_w<<<504, 256, 0, stream>>>(gc1_Ws, gc1_Wn, gc2_Ws, gc2_Wn, W1H, W2H);
  k_prep_d1<<<32, 256, 0, stream>>>(d1W, D1H);

  // main pipeline
  k_gcm<80, 5><<<3909, 256, 0, stream>>>(featH, adjs, W1H, gc1_b,
                                         bn1g, bn1b, bn1m, bn1v, hA);
  k_pool_h<<<15625, 256, 0, stream>>>((const f16x8*)hA, adjs, (f16x8*)hB);
  k_gcm<64, 4><<<3909, 256, 0, stream>>>(hB, adjs, W2H, gc2_b,
                                         bn1g, bn1b, bn1m, bn1v, hC);
  k_pool_h<<<15625, 256, 0, stream>>>((const f16x8*)hC, adjs, (f16x8*)hD);
  k_dense1f<<<1024, 256, 0, stream>>>((const __half2*)hD, list, start, hist, D1H, d1b,
                                      bn3g, bn3b, bn3m, bn3v, g);
  k_dense23<<<1024, 64, 0, stream>>>(g, d2W, d2b, d3W, d3b, out);
}

// Round 4
// 688.510 us; speedup vs baseline: 1.1721x; 1.0278x over previous
//
#include <hip/hip_runtime.h>
#include <hip/hip_fp16.h>
#include <math.h>

// DEG_COUNTS = [20000, 80000, 150000, 150000, 75000, 20000, 5000]
// OFF        = [0, 20000, 100000, 250000, 400000, 475000, 495000, 500000]
// N_ATOMS = 500000, BATCH = 1024, F_IN = 75

struct AdjPtrs { const int* p[6]; };

typedef _Float16 f16x8 __attribute__((ext_vector_type(8)));
typedef float f32x4 __attribute__((ext_vector_type(4)));

__device__ __forceinline__ float tanh_fast(float x) {
  float ax = fabsf(x);
  float r = __expf(-2.f * ax);             // r in (0,1], never inf
  float t = 1.f - 2.f * r * __builtin_amdgcn_rcpf(1.f + r);
  return copysignf(t, x);
}

__device__ __forceinline__ f16x8 max8(f16x8 a, f16x8 b) {
  #pragma unroll
  for (int i = 0; i < 8; i++) a[i] = (a[i] > b[i]) ? a[i] : b[i];  // -> v_pk_max_f16
  return a;
}

// ---------------- membership counting sort ----------------
__global__ __launch_bounds__(256) void k_zero_hist(int* __restrict__ hist) {
  int i = blockIdx.x * 256 + threadIdx.x;
  if (i < 1024) hist[i] = 0;
}

__global__ __launch_bounds__(256) void k_hist(const int* __restrict__ mem, int* __restrict__ hist) {
  __shared__ int lh[1024];
  int tid = threadIdx.x;
  for (int i = tid; i < 1024; i += 256) lh[i] = 0;
  __syncthreads();
  int stride = gridDim.x * 256;
  for (int i = blockIdx.x * 256 + tid; i < 500000; i += stride)
    atomicAdd(&lh[mem[i]], 1);
  __syncthreads();
  for (int i = tid; i < 1024; i += 256) {
    int v = lh[i];
    if (v) atomicAdd(&hist[i], v);
  }
}

__global__ __launch_bounds__(1024) void k_scan(const int* __restrict__ hist,
                                               int* __restrict__ start,
                                               int* __restrict__ cursor) {
  __shared__ int sc[1024];
  int t = threadIdx.x;
  int h = hist[t];
  sc[t] = h;
  __syncthreads();
  for (int off = 1; off < 1024; off <<= 1) {
    int v = (t >= off) ? sc[t - off] : 0;
    __syncthreads();
    sc[t] += v;
    __syncthreads();
  }
  int ex = sc[t] - h;
  start[t] = ex;
  cursor[t] = ex;
}

__global__ __launch_bounds__(256) void k_scatter(const int* __restrict__ mem,
                                                 int* __restrict__ cursor,
                                                 int* __restrict__ list) {
  int i = blockIdx.x * 256 + threadIdx.x;
  if (i < 500000) {
    int pos = atomicAdd(&cursor[mem[i]], 1);
    list[pos] = i;
  }
}

// ---------------- prep: feat fp32[500k x 75] -> fp16 padded [500k x 80] ----------------
__global__ __launch_bounds__(256) void k_prep(const float* __restrict__ feat,
                                              __half2* __restrict__ featH2) {
  int i = blockIdx.x * 256 + threadIdx.x;  // 20,000,000 exactly
  int a = i / 40;
  int jp = i - a * 40;
  int kk = jp * 2;
  float v0 = (kk < 75) ? feat[(size_t)a * 75 + kk] : 0.f;
  float v1 = (kk + 1 < 75) ? feat[(size_t)a * 75 + kk + 1] : 0.f;
  featH2[i] = __floats2half2_rn(v0, v1);
}

// ---------------- prep: W -> fp16 in MFMA B-fragment order ----------------
// Layout per layer: [d][c][ns][lane][j=0..7] where the element is
// B[n][k] = W[k][n], n = ns*16 + (lane&15), k = c*32 + (lane>>4)*8 + j.
__global__ __launch_bounds__(256) void k_prep_w(
    const float* __restrict__ Ws1, const float* __restrict__ Wn1,
    const float* __restrict__ Ws2, const float* __restrict__ Wn2,
    __half* __restrict__ W1H, __half* __restrict__ W2H) {
  int i = blockIdx.x * 256 + threadIdx.x;  // 129024 exactly
  if (i < 71680) {  // layer1: 7 * (5*4*64*8) = 7*10240, KP=160
    int d = i / 10240, r = i - d * 10240;
    int j = r & 7, lane = (r >> 3) & 63, t = r >> 9;  // t = c*4+ns, 0..19
    int n = (t & 3) * 16 + (lane & 15);
    int k = (t >> 2) * 32 + (lane >> 4) * 8 + j;
    float v = 0.f;
    if (k < 75) v = Ws1[d * 4800 + k * 64 + n];
    else if (k >= 80 && k < 155 && d > 0) v = Wn1[(d - 1) * 4800 + (k - 80) * 64 + n];
    W1H[i] = __float2half(v);
  } else {  // layer2: 7 * (4*4*64*8) = 7*8192, KP=128
    int i2 = i - 71680;
    int d = i2 / 8192, r = i2 - d * 8192;
    int j = r & 7, lane = (r >> 3) & 63, t = r >> 9;  // 0..15
    int n = (t & 3) * 16 + (lane & 15);
    int k = (t >> 2) * 32 + (lane >> 4) * 8 + j;
    float v = 0.f;
    if (k < 64) v = Ws2[d * 4096 + k * 64 + n];
    else if (d > 0) v = Wn2[(d - 1) * 4096 + (k - 64) * 64 + n];
    W2H[i2] = __float2half(v);
  }
}

// ---------------- prep: d1_W (64x128 fp32) -> hi/lo fp16 [2][128][64] ----------------
// D1H[hl*8192 + n*64 + k] = B[n][k] (= d1_W[k][n]) -- already MFMA B-fragment
// order: 8 contiguous halves at (n, k=ks*32+q*8) are one 16B fragment.
__global__ __launch_bounds__(256) void k_prep_d1(const float* __restrict__ W,
                                                 __half* __restrict__ D1H) {
  int i = blockIdx.x * 256 + threadIdx.x;  // 8192 exactly
  int n = i >> 6, k = i & 63;
  float v = W[k * 128 + n];
  __half hi = __float2half(v);
  D1H[i] = hi;
  D1H[8192 + i] = __float2half(v - __half2float(hi));
}

// ---------------- fused graph_conv (MFMA) + tanh + bn1, fp16 in/out ----------------
// Each wave owns 16 atoms (acc[4] = 16 AGPR). Register-direct A gathers from
// global, no LDS/barriers. Tiny live set -> 6 waves/SIMD for gather-latency
// hiding; per-atom gather & MFMA counts unchanged vs larger tiles.
template<int FP, int NCH, int D>
__device__ __forceinline__ void gcm_run(
    const __half* __restrict__ featH, const int* __restrict__ adj_g,
    int abase, int na, const f16x8* __restrict__ Wf,
    const float* __restrict__ bias_d,
    const float* __restrict__ bng, const float* __restrict__ bnb,
    const float* __restrict__ bnm, const float* __restrict__ bnv,
    __half* __restrict__ out) {
  int tid = threadIdx.x;
  int lane = tid & 63, w = tid >> 6;
  int ln = lane & 15, q = lane >> 4;
  int m = w * 16 + ln;  // this wave's A row (atom within block)

  // adjacency row for this lane, clamped for the tail
  int ar[D > 0 ? D : 1];
  if (D > 0) {
    bool ok = (m < na);
    #pragma unroll
    for (int e = 0; e < D; e++) ar[e] = ok ? adj_g[m * D + e] : 0;
  }

  f32x4 acc[4];
  #pragma unroll
  for (int ns = 0; ns < 4; ns++) {
    float bj = bias_d[ns * 16 + ln];
    acc[ns] = (f32x4){bj, bj, bj, bj};
  }

  #pragma unroll
  for (int c = 0; c < NCH; c++) {
    int ksg = c * 32 + q * 8;
    f16x8 af;
    if (ksg < FP) {
      af = *(const f16x8*)(featH + (size_t)(abase + m) * FP + ksg);
    } else if (D > 0) {
      int kb = ksg - FP;
      f16x8 v = *(const f16x8*)(featH + (size_t)ar[0] * FP + kb);
      #pragma unroll
      for (int e = 1; e < D; e++) {
        f16x8 u = *(const f16x8*)(featH + (size_t)ar[e] * FP + kb);
        v = v + u;
      }
      af = v;
    } else {
      af = (f16x8){};
    }
    #pragma unroll
    for (int ns = 0; ns < 4; ns++) {
      f16x8 bf = Wf[(c * 4 + ns) * 64 + lane];
      acc[ns] = __builtin_amdgcn_mfma_f32_16x16x32_f16(af, bf, acc[ns], 0, 0, 0);
    }
  }

  // epilogue: tanh + bn, store fp16. D layout: col=lane&15, row=(lane>>4)*4+reg
  #pragma unroll
  for (int ns = 0; ns < 4; ns++) {
    int j = ns * 16 + ln;
    float scv = bng[j] * rsqrtf(bnv[j] + 1e-3f);
    float shv = bnb[j] - bnm[j] * scv;
    #pragma unroll
    for (int r = 0; r < 4; r++) {
      int atom = w * 16 + q * 4 + r;
      if (atom < na)
        out[(size_t)(abase + atom) * 64 + j] =
            __float2half(tanh_fast(acc[ns][r]) * scv + shv);
    }
  }
}

template<int FP, int NCH>
__global__ __launch_bounds__(256, 6) void k_gcm(
    const __half* __restrict__ featH, AdjPtrs adjs,
    const __half* __restrict__ WtH, const float* __restrict__ bias,
    const float* __restrict__ bng, const float* __restrict__ bnb,
    const float* __restrict__ bnm, const float* __restrict__ bnv,
    __half* __restrict__ out) {
  int bid = blockIdx.x;  // 7815 blocks of 64 atoms
  int d, off, end, bloc;
  if      (bid < 313)  { d = 0; bloc = bid;        off = 0;      end = 20000;  }
  else if (bid < 1563) { d = 1; bloc = bid - 313;  off = 20000;  end = 100000; }
  else if (bid < 3907) { d = 2; bloc = bid - 1563; off = 100000; end = 250000; }
  else if (bid < 6251) { d = 3; bloc = bid - 3907; off = 250000; end = 400000; }
  else if (bid < 7423) { d = 4; bloc = bid - 6251; off = 400000; end = 475000; }
  else if (bid < 7736) { d = 5; bloc = bid - 7423; off = 475000; end = 495000; }
  else                 { d = 6; bloc = bid - 7736; off = 495000; end = 500000; }
  int abase = off + bloc * 64;
  int na = min(64, end - abase);
  const int* adj_g = (d > 0) ? adjs.p[d - 1] + (abase - off) * d : (const int*)0;
  const f16x8* Wf = (const f16x8*)WtH + d * (NCH * 4 * 64);
  const float* bias_d = bias + d * 64;

  switch (d) {
    case 0: gcm_run<FP, NCH, 0>(featH, adj_g, abase, na, Wf, bias_d, bng, bnb, bnm, bnv, out); break;
    case 1: gcm_run<FP, NCH, 1>(featH, adj_g, abase, na, Wf, bias_d, bng, bnb, bnm, bnv, out); break;
    case 2: gcm_run<FP, NCH, 2>(featH, adj_g, abase, na, Wf, bias_d, bng, bnb, bnm, bnv, out); break;
    case 3: gcm_run<FP, NCH, 3>(featH, adj_g, abase, na, Wf, bias_d, bng, bnb, bnm, bnv, out); break;
    case 4: gcm_run<FP, NCH, 4>(featH, adj_g, abase, na, Wf, bias_d, bng, bnb, bnm, bnv, out); break;
    case 5: gcm_run<FP, NCH, 5>(featH, adj_g, abase, na, Wf, bias_d, bng, bnb, bnm, bnv, out); break;
    default: gcm_run<FP, NCH, 6>(featH, adj_g, abase, na, Wf, bias_d, bng, bnb, bnm, bnv, out); break;
  }
}

// ---------------- graph_pool fp16, 16B segments + packed max ----------------
template<int D>
__device__ __forceinline__ f16x8 pool_h_acc(const f16x8* __restrict__ in8,
                                            const int* __restrict__ ad, int sg, f16x8 v) {
  #pragma unroll
  for (int e = 0; e < D; e++) v = max8(v, in8[ad[e] * 8 + sg]);
  return v;
}

__global__ __launch_bounds__(256) void k_pool_h(const f16x8* __restrict__ in8, AdjPtrs adjs,
                                                f16x8* __restrict__ out8) {
  int t = blockIdx.x * 256 + threadIdx.x;  // 4,000,000 exactly
  int atom = t >> 3, sg = t & 7;
  int d, off;
  if      (atom < 20000)  { d = 0; off = 0;      }
  else if (atom < 100000) { d = 1; off = 20000;  }
  else if (atom < 250000) { d = 2; off = 100000; }
  else if (atom < 400000) { d = 3; off = 250000; }
  else if (atom < 475000) { d = 4; off = 400000; }
  else if (atom < 495000) { d = 5; off = 475000; }
  else                    { d = 6; off = 495000; }
  f16x8 v = in8[atom * 8 + sg];
  if (d > 0) {
    const int* ad = adjs.p[d - 1] + (atom - off) * d;
    switch (d) {
      case 1: v = pool_h_acc<1>(in8, ad, sg, v); break;
      case 2: v = pool_h_acc<2>(in8, ad, sg, v); break;
      case 3: v = pool_h_acc<3>(in8, ad, sg, v); break;
      case 4: v = pool_h_acc<4>(in8, ad, sg, v); break;
      case 5: v = pool_h_acc<5>(in8, ad, sg, v); break;
      default: v = pool_h_acc<6>(in8, ad, sg, v); break;
    }
  }
  out8[atom * 8 + sg] = v;
}

// ---------------- fused dense1(MFMA, hi/lo W) + tanh + bn3 + segment sum/max + tanh ----
// Barrier-free rewrite: A-fragment rows gathered register-direct via list[],
// B-fragments read straight from D1H (global, 32 KB, L1-hot, already in
// fragment order). No LDS at all; tail rows index-clamped and masked in the
// epilogue. Chunk accumulation order (bias -> lo ks0,ks1 -> hi ks0,ks1)
// preserved for bit-identical numerics vs the staged version.
__global__ __launch_bounds__(256, 4) void k_dense1f(
    const __half* __restrict__ hD, const int* __restrict__ list,
    const int* __restrict__ start, const int* __restrict__ hist,
    const __half* __restrict__ D1H, const float* __restrict__ d1b,
    const float* __restrict__ g3, const float* __restrict__ b3,
    const float* __restrict__ m3, const float* __restrict__ v3,
    float* __restrict__ g) {
  int b = blockIdx.x, tid = threadIdx.x;
  int lane = tid & 63, w = tid >> 6;
  int ln = lane & 15, q = lane >> 4;
  int stt = start[b], cnt = hist[b];

  float bj[2], sc[2], sh[2];
  #pragma unroll
  for (int nf = 0; nf < 2; nf++) {
    int col = w * 32 + nf * 16 + ln;
    bj[nf] = d1b[col];
    sc[nf] = g3[col] * rsqrtf(v3[col] + 1e-3f);
    sh[nf] = b3[col] - m3[col] * sc[nf];
  }

  float sum[2] = {0.f, 0.f};
  float mx[2] = {-INFINITY, -INFINITY};

  for (int cb = 0; cb < cnt; cb += 64) {
    int nr = min(64, cnt - cb);
    // this lane's 4 A rows (mf*16+ln), tail-clamped to a valid index
    int ridx[4];
    #pragma unroll
    for (int mf = 0; mf < 4; mf++) {
      int row = mf * 16 + ln;
      ridx[mf] = list[stt + cb + min(row, nr - 1)];
    }

    f32x4 acc[4][2];
    #pragma unroll
    for (int mf = 0; mf < 4; mf++)
      #pragma unroll
      for (int nf = 0; nf < 2; nf++) acc[mf][nf] = (f32x4){bj[nf], bj[nf], bj[nf], bj[nf]};

    #pragma unroll
    for (int hl = 1; hl >= 0; hl--) {
      #pragma unroll
      for (int ks = 0; ks < 2; ks++) {
        f16x8 af[4];
        #pragma unroll
        for (int mf = 0; mf < 4; mf++)
          af[mf] = *(const f16x8*)(hD + (size_t)ridx[mf] * 64 + ks * 32 + q * 8);
        #pragma unroll
        for (int nf = 0; nf < 2; nf++) {
          f16x8 bf = *(const f16x8*)(D1H + hl * 8192 +
                                     (w * 32 + nf * 16 + ln) * 64 + ks * 32 + q * 8);
          #pragma unroll
          for (int mf = 0; mf < 4; mf++)
            acc[mf][nf] = __builtin_amdgcn_mfma_f32_16x16x32_f16(af[mf], bf, acc[mf][nf], 0, 0, 0);
        }
      }
    }

    #pragma unroll
    for (int mf = 0; mf < 4; mf++) {
      #pragma unroll
      for (int nf = 0; nf < 2; nf++) {
        #pragma unroll
        for (int r = 0; r < 4; r++) {
          int row = mf * 16 + q * 4 + r;
          if (row < nr) {
            float v = tanh_fast(acc[mf][nf][r]) * sc[nf] + sh[nf];
            sum[nf] += v;
            mx[nf] = fmaxf(mx[nf], v);
          }
        }
      }
    }
  }

  #pragma unroll
  for (int nf = 0; nf < 2; nf++) {
    sum[nf] += __shfl_xor(sum[nf], 16);
    sum[nf] += __shfl_xor(sum[nf], 32);
    mx[nf] = fmaxf(mx[nf], __shfl_xor(mx[nf], 16));
    mx[nf] = fmaxf(mx[nf], __shfl_xor(mx[nf], 32));
  }
  if (q == 0) {
    #pragma unroll
    for (int nf = 0; nf < 2; nf++) {
      int col = w * 32 + nf * 16 + ln;
      g[b * 256 + col] = tanh_fast(sum[nf]);
      g[b * 256 + 128 + col] = tanh_fast(mx[nf]);
    }
  }
}

// ---------------- dense2 -> sigmoid -> dense3 ----------------
__global__ __launch_bounds__(64) void k_dense23(
    const float* __restrict__ g, const float* __restrict__ W2,
    const float* __restrict__ b2, const float* __restrict__ W3,
    const float* __restrict__ b3, float* __restrict__ out) {
  __shared__ float gr[256];
  int b = blockIdx.x, j = threadIdx.x;
  ((float4*)gr)[j] = ((const float4*)(g + b * 256))[j];
  __syncthreads();
  float acc = b2[j];
  #pragma unroll 8
  for (int k = 0; k < 256; k++) acc += gr[k] * W2[k * 64 + j];
  float sg = 1.f / (1.f + expf(-acc));
  float p = sg * W3[j];
  #pragma unroll
  for (int off = 32; off >= 1; off >>= 1) p += __shfl_xor(p, off);
  if (j == 0) out[b] = p + b3[0];
}

// ---------------- launch ----------------
extern "C" void kernel_launch(void* const* d_in, const int* in_sizes, int n_in,
                              void* d_out, int out_size, void* d_ws, size_t ws_size,
                              hipStream_t stream) {
  const float* feat = (const float*)d_in[0];
  const int*   mem  = (const int*)d_in[1];
  AdjPtrs adjs;
  for (int i = 0; i < 6; i++) adjs.p[i] = (const int*)d_in[2 + i];
  const float* gc1_Wn = (const float*)d_in[8];
  const float* gc1_Ws = (const float*)d_in[9];
  const float* gc1_b  = (const float*)d_in[10];
  const float* gc2_Wn = (const float*)d_in[11];
  const float* gc2_Ws = (const float*)d_in[12];
  const float* gc2_b  = (const float*)d_in[13];
  const float* bn1g = (const float*)d_in[14];
  const float* bn1b = (const float*)d_in[15];
  const float* bn1m = (const float*)d_in[16];
  const float* bn1v = (const float*)d_in[17];
  const float* bn3g = (const float*)d_in[18];
  const float* bn3b = (const float*)d_in[19];
  const float* bn3m = (const float*)d_in[20];
  const float* bn3v = (const float*)d_in[21];
  const float* d1W = (const float*)d_in[22];
  const float* d1b = (const float*)d_in[23];
  const float* d2W = (const float*)d_in[24];
  const float* d2b = (const float*)d_in[25];
  const float* d3W = (const float*)d_in[26];
  const float* d3b = (const float*)d_in[27];
  float* out = (float*)d_out;

  char* w = (char*)d_ws;
  __half* featH = (__half*)(w);
  __half* hA    = (__half*)(w + 80000000LL);
  __half* hB    = (__half*)(w + 144000000LL);
  __half* hC    = (__half*)(w);              // gc2 out (featH dead)
  __half* hD    = (__half*)(w + 80000000LL); // pool2 out (hA dead)
  __half* W1H   = (__half*)(w + 210000000LL);
  __half* W2H   = (__half*)(w + 210200000LL);
  __half* D1H   = (__half*)(w + 210330000LL);  // 32 KB hi/lo
  float*  g     = (float*)(w + 210400000LL);   // 1 MB
  int* hist     = (int*)(w + 211600000LL);
  int* start    = (int*)(w + 211604096LL);
  int* cursor   = (int*)(w + 211608192LL);
  int* list     = (int*)(w + 211612288LL);     // 2 MB

  // membership counting sort
  k_zero_hist<<<4, 256, 0, stream>>>(hist);
  k_hist<<<512, 256, 0, stream>>>(mem, hist);
  k_scan<<<1, 1024, 0, stream>>>(hist, start, cursor);
  k_scatter<<<1954, 256, 0, stream>>>(mem, cursor, list);

  // prep
  k_prep<<<78125, 256, 0, stream>>>(feat, (__half2*)featH);
  k_prep_w<<<504, 256, 0, stream>>>(gc1_Ws, gc1_Wn, gc2_Ws, gc2_Wn, W1H, W2H);
  k_prep_d1<<<32, 256, 0, stream>>>(d1W, D1H);

  // main pipeline
  k_gcm<80, 5><<<7815, 256, 0, stream>>>(featH, adjs, W1H, gc1_b,
                                         bn1g, bn1b, bn1m, bn1v, hA);
  k_pool_h<<<15625, 256, 0, stream>>>((const f16x8*)hA, adjs, (f16x8*)hB);
  k_gcm<64, 4><<<7815, 256, 0, stream>>>(hB, adjs, W2H, gc2_b,
                                         bn1g, bn1b, bn1m, bn1v, hC);
  k_pool_h<<<15625, 256, 0, stream>>>((const f16x8*)hC, adjs, (f16x8*)hD);
  k_dense1f<<<1024, 256, 0, stream>>>((const __half*)hD, list, start, hist, D1H, d1b,
                                      bn3g, bn3b, bn3m, bn3v, g);
  k_dense23<<<1024, 64, 0, stream>>>(g, d2W, d2b, d3W, d3b, out);
}

// Round 5
// 591.968 us; speedup vs baseline: 1.3633x; 1.1631x over previous
//
#include <hip/hip_runtime.h>
#include <hip/hip_fp16.h>
#include <math.h>

// DEG_COUNTS = [20000, 80000, 150000, 150000, 75000, 20000, 5000]
// OFF        = [0, 20000, 100000, 250000, 400000, 475000, 495000, 500000]
// N_ATOMS = 500000, BATCH = 1024, F_IN = 75

struct AdjPtrs { const int* p[6]; };

typedef _Float16 f16x8 __attribute__((ext_vector_type(8)));
typedef float f32x4 __attribute__((ext_vector_type(4)));

#define SORT_NB 512
#define SORT_CHUNK 977  // 512 * 977 = 500224 >= 500000

__device__ __forceinline__ float tanh_fast(float x) {
  float ax = fabsf(x);
  float r = __expf(-2.f * ax);             // r in (0,1], never inf
  float t = 1.f - 2.f * r * __builtin_amdgcn_rcpf(1.f + r);
  return copysignf(t, x);
}

__device__ __forceinline__ f16x8 max8(f16x8 a, f16x8 b) {
  #pragma unroll
  for (int i = 0; i < 8; i++) a[i] = (a[i] > b[i]) ? a[i] : b[i];  // -> v_pk_max_f16
  return a;
}

// ---------------- membership counting sort (two-level, no global atomics) ----------------
// Phase A: per-block LDS histogram -> hist2[blk][1024]
__global__ __launch_bounds__(256) void k_hist_blk(const int* __restrict__ mem,
                                                  int* __restrict__ hist2) {
  __shared__ int lh[1024];
  int blk = blockIdx.x, tid = threadIdx.x;
  for (int i = tid; i < 1024; i += 256) lh[i] = 0;
  __syncthreads();
  int base = blk * SORT_CHUNK;
  int end = min(base + SORT_CHUNK, 500000);
  for (int i = base + tid; i < end; i += 256)
    atomicAdd(&lh[mem[i]], 1);
  __syncthreads();
  for (int i = tid; i < 1024; i += 256)
    hist2[blk * 1024 + i] = lh[i];
}

// Phase B: one block per key; exclusive prefix over the 512 blocks (in place),
// per-key total -> hist[key]
__global__ __launch_bounds__(512) void k_scan_blk(int* __restrict__ hist2,
                                                  int* __restrict__ hist) {
  __shared__ int sc[SORT_NB];
  int key = blockIdx.x, t = threadIdx.x;
  int v = hist2[t * 1024 + key];
  sc[t] = v;
  __syncthreads();
  for (int off = 1; off < SORT_NB; off <<= 1) {
    int u = (t >= off) ? sc[t - off] : 0;
    __syncthreads();
    sc[t] += u;
    __syncthreads();
  }
  hist2[t * 1024 + key] = sc[t] - v;  // exclusive over blocks
  if (t == SORT_NB - 1) hist[key] = sc[SORT_NB - 1];
}

// Phase C (over keys): exclusive prefix of hist -> start
__global__ __launch_bounds__(1024) void k_scan(const int* __restrict__ hist,
                                               int* __restrict__ start) {
  __shared__ int sc[1024];
  int t = threadIdx.x;
  int h = hist[t];
  sc[t] = h;
  __syncthreads();
  for (int off = 1; off < 1024; off <<= 1) {
    int v = (t >= off) ? sc[t - off] : 0;
    __syncthreads();
    sc[t] += v;
    __syncthreads();
  }
  start[t] = sc[t] - h;
}

// Phase D: scatter with LDS-only rank atomics
__global__ __launch_bounds__(256) void k_scatter_blk(const int* __restrict__ mem,
                                                     const int* __restrict__ start,
                                                     const int* __restrict__ hist2,
                                                     int* __restrict__ list) {
  __shared__ int lh[1024];
  int blk = blockIdx.x, tid = threadIdx.x;
  for (int i = tid; i < 1024; i += 256) lh[i] = 0;
  __syncthreads();
  int base = blk * SORT_CHUNK;
  int end = min(base + SORT_CHUNK, 500000);
  for (int i = base + tid; i < end; i += 256) {
    int key = mem[i];
    int r = atomicAdd(&lh[key], 1);
    list[start[key] + hist2[blk * 1024 + key] + r] = i;
  }
}

// ---------------- prep: feat fp32[500k x 75] -> fp16 padded [500k x 80] ----------------
__global__ __launch_bounds__(256) void k_prep(const float* __restrict__ feat,
                                              __half2* __restrict__ featH2) {
  int i = blockIdx.x * 256 + threadIdx.x;  // 20,000,000 exactly
  int a = i / 40;
  int jp = i - a * 40;
  int kk = jp * 2;
  float v0 = (kk < 75) ? feat[(size_t)a * 75 + kk] : 0.f;
  float v1 = (kk + 1 < 75) ? feat[(size_t)a * 75 + kk + 1] : 0.f;
  featH2[i] = __floats2half2_rn(v0, v1);
}

// ---------------- prep: W -> fp16 in MFMA B-fragment order ----------------
// Layout per layer: [d][c][ns][lane][j=0..7] where the element is
// B[n][k] = W[k][n], n = ns*16 + (lane&15), k = c*32 + (lane>>4)*8 + j.
__global__ __launch_bounds__(256) void k_prep_w(
    const float* __restrict__ Ws1, const float* __restrict__ Wn1,
    const float* __restrict__ Ws2, const float* __restrict__ Wn2,
    __half* __restrict__ W1H, __half* __restrict__ W2H) {
  int i = blockIdx.x * 256 + threadIdx.x;  // 129024 exactly
  if (i < 71680) {  // layer1: 7 * (5*4*64*8) = 7*10240, KP=160
    int d = i / 10240, r = i - d * 10240;
    int j = r & 7, lane = (r >> 3) & 63, t = r >> 9;  // t = c*4+ns, 0..19
    int n = (t & 3) * 16 + (lane & 15);
    int k = (t >> 2) * 32 + (lane >> 4) * 8 + j;
    float v = 0.f;
    if (k < 75) v = Ws1[d * 4800 + k * 64 + n];
    else if (k >= 80 && k < 155 && d > 0) v = Wn1[(d - 1) * 4800 + (k - 80) * 64 + n];
    W1H[i] = __float2half(v);
  } else {  // layer2: 7 * (4*4*64*8) = 7*8192, KP=128
    int i2 = i - 71680;
    int d = i2 / 8192, r = i2 - d * 8192;
    int j = r & 7, lane = (r >> 3) & 63, t = r >> 9;  // 0..15
    int n = (t & 3) * 16 + (lane & 15);
    int k = (t >> 2) * 32 + (lane >> 4) * 8 + j;
    float v = 0.f;
    if (k < 64) v = Ws2[d * 4096 + k * 64 + n];
    else if (d > 0) v = Wn2[(d - 1) * 4096 + (k - 64) * 64 + n];
    W2H[i2] = __float2half(v);
  }
}

// ---------------- prep: d1_W (64x128 fp32) -> hi/lo fp16 [2][128][64] ----------------
// D1H[hl*8192 + n*64 + k] = B[n][k] (= d1_W[k][n]) -- already MFMA B-fragment
// order: 8 contiguous halves at (n, k=ks*32+q*8) are one 16B fragment.
__global__ __launch_bounds__(256) void k_prep_d1(const float* __restrict__ W,
                                                 __half* __restrict__ D1H) {
  int i = blockIdx.x * 256 + threadIdx.x;  // 8192 exactly
  int n = i >> 6, k = i & 63;
  float v = W[k * 128 + n];
  __half hi = __float2half(v);
  D1H[i] = hi;
  D1H[8192 + i] = __float2half(v - __half2float(hi));
}

// ---------------- fused graph_conv (MFMA) + tanh + bn1, fp16 in/out ----------------
// Each wave owns 16 atoms (acc[4] = 16 AGPR). Register-direct A gathers from
// global, no LDS/barriers. Tiny live set -> 6 waves/SIMD for gather-latency
// hiding; per-atom gather & MFMA counts unchanged vs larger tiles.
template<int FP, int NCH, int D>
__device__ __forceinline__ void gcm_run(
    const __half* __restrict__ featH, const int* __restrict__ adj_g,
    int abase, int na, const f16x8* __restrict__ Wf,
    const float* __restrict__ bias_d,
    const float* __restrict__ bng, const float* __restrict__ bnb,
    const float* __restrict__ bnm, const float* __restrict__ bnv,
    __half* __restrict__ out) {
  int tid = threadIdx.x;
  int lane = tid & 63, w = tid >> 6;
  int ln = lane & 15, q = lane >> 4;
  int m = w * 16 + ln;  // this wave's A row (atom within block)

  // adjacency row for this lane, clamped for the tail
  int ar[D > 0 ? D : 1];
  if (D > 0) {
    bool ok = (m < na);
    #pragma unroll
    for (int e = 0; e < D; e++) ar[e] = ok ? adj_g[m * D + e] : 0;
  }

  f32x4 acc[4];
  #pragma unroll
  for (int ns = 0; ns < 4; ns++) {
    float bj = bias_d[ns * 16 + ln];
    acc[ns] = (f32x4){bj, bj, bj, bj};
  }

  #pragma unroll
  for (int c = 0; c < NCH; c++) {
    int ksg = c * 32 + q * 8;
    f16x8 af;
    if (ksg < FP) {
      af = *(const f16x8*)(featH + (size_t)(abase + m) * FP + ksg);
    } else if (D > 0) {
      int kb = ksg - FP;
      f16x8 v = *(const f16x8*)(featH + (size_t)ar[0] * FP + kb);
      #pragma unroll
      for (int e = 1; e < D; e++) {
        f16x8 u = *(const f16x8*)(featH + (size_t)ar[e] * FP + kb);
        v = v + u;
      }
      af = v;
    } else {
      af = (f16x8){};
    }
    #pragma unroll
    for (int ns = 0; ns < 4; ns++) {
      f16x8 bf = Wf[(c * 4 + ns) * 64 + lane];
      acc[ns] = __builtin_amdgcn_mfma_f32_16x16x32_f16(af, bf, acc[ns], 0, 0, 0);
    }
  }

  // epilogue: tanh + bn, store fp16. D layout: col=lane&15, row=(lane>>4)*4+reg
  #pragma unroll
  for (int ns = 0; ns < 4; ns++) {
    int j = ns * 16 + ln;
    float scv = bng[j] * rsqrtf(bnv[j] + 1e-3f);
    float shv = bnb[j] - bnm[j] * scv;
    #pragma unroll
    for (int r = 0; r < 4; r++) {
      int atom = w * 16 + q * 4 + r;
      if (atom < na)
        out[(size_t)(abase + atom) * 64 + j] =
            __float2half(tanh_fast(acc[ns][r]) * scv + shv);
    }
  }
}

template<int FP, int NCH>
__global__ __launch_bounds__(256, 6) void k_gcm(
    const __half* __restrict__ featH, AdjPtrs adjs,
    const __half* __restrict__ WtH, const float* __restrict__ bias,
    const float* __restrict__ bng, const float* __restrict__ bnb,
    const float* __restrict__ bnm, const float* __restrict__ bnv,
    __half* __restrict__ out) {
  int bid = blockIdx.x;  // 7815 blocks of 64 atoms
  int d, off, end, bloc;
  if      (bid < 313)  { d = 0; bloc = bid;        off = 0;      end = 20000;  }
  else if (bid < 1563) { d = 1; bloc = bid - 313;  off = 20000;  end = 100000; }
  else if (bid < 3907) { d = 2; bloc = bid - 1563; off = 100000; end = 250000; }
  else if (bid < 6251) { d = 3; bloc = bid - 3907; off = 250000; end = 400000; }
  else if (bid < 7423) { d = 4; bloc = bid - 6251; off = 400000; end = 475000; }
  else if (bid < 7736) { d = 5; bloc = bid - 7423; off = 475000; end = 495000; }
  else                 { d = 6; bloc = bid - 7736; off = 495000; end = 500000; }
  int abase = off + bloc * 64;
  int na = min(64, end - abase);
  const int* adj_g = (d > 0) ? adjs.p[d - 1] + (abase - off) * d : (const int*)0;
  const f16x8* Wf = (const f16x8*)WtH + d * (NCH * 4 * 64);
  const float* bias_d = bias + d * 64;

  switch (d) {
    case 0: gcm_run<FP, NCH, 0>(featH, adj_g, abase, na, Wf, bias_d, bng, bnb, bnm, bnv, out); break;
    case 1: gcm_run<FP, NCH, 1>(featH, adj_g, abase, na, Wf, bias_d, bng, bnb, bnm, bnv, out); break;
    case 2: gcm_run<FP, NCH, 2>(featH, adj_g, abase, na, Wf, bias_d, bng, bnb, bnm, bnv, out); break;
    case 3: gcm_run<FP, NCH, 3>(featH, adj_g, abase, na, Wf, bias_d, bng, bnb, bnm, bnv, out); break;
    case 4: gcm_run<FP, NCH, 4>(featH, adj_g, abase, na, Wf, bias_d, bng, bnb, bnm, bnv, out); break;
    case 5: gcm_run<FP, NCH, 5>(featH, adj_g, abase, na, Wf, bias_d, bng, bnb, bnm, bnv, out); break;
    default: gcm_run<FP, NCH, 6>(featH, adj_g, abase, na, Wf, bias_d, bng, bnb, bnm, bnv, out); break;
  }
}

// ---------------- graph_pool fp16, 16B segments + packed max ----------------
template<int D>
__device__ __forceinline__ f16x8 pool_h_acc(const f16x8* __restrict__ in8,
                                            const int* __restrict__ ad, int sg, f16x8 v) {
  #pragma unroll
  for (int e = 0; e < D; e++) v = max8(v, in8[ad[e] * 8 + sg]);
  return v;
}

__global__ __launch_bounds__(256) void k_pool_h(const f16x8* __restrict__ in8, AdjPtrs adjs,
                                                f16x8* __restrict__ out8) {
  int t = blockIdx.x * 256 + threadIdx.x;  // 4,000,000 exactly
  int atom = t >> 3, sg = t & 7;
  int d, off;
  if      (atom < 20000)  { d = 0; off = 0;      }
  else if (atom < 100000) { d = 1; off = 20000;  }
  else if (atom < 250000) { d = 2; off = 100000; }
  else if (atom < 400000) { d = 3; off = 250000; }
  else if (atom < 475000) { d = 4; off = 400000; }
  else if (atom < 495000) { d = 5; off = 475000; }
  else                    { d = 6; off = 495000; }
  f16x8 v = in8[atom * 8 + sg];
  if (d > 0) {
    const int* ad = adjs.p[d - 1] + (atom - off) * d;
    switch (d) {
      case 1: v = pool_h_acc<1>(in8, ad, sg, v); break;
      case 2: v = pool_h_acc<2>(in8, ad, sg, v); break;
      case 3: v = pool_h_acc<3>(in8, ad, sg, v); break;
      case 4: v = pool_h_acc<4>(in8, ad, sg, v); break;
      case 5: v = pool_h_acc<5>(in8, ad, sg, v); break;
      default: v = pool_h_acc<6>(in8, ad, sg, v); break;
    }
  }
  out8[atom * 8 + sg] = v;
}

// ---------------- fused dense1(MFMA, hi/lo W) + tanh + bn3 + segment sum/max + tanh ----
// Barrier-free: A-fragment rows gathered register-direct via list[],
// B-fragments read straight from D1H (global, 32 KB, L1-hot, already in
// fragment order). No LDS at all; tail rows index-clamped and masked in the
// epilogue.
__global__ __launch_bounds__(256, 4) void k_dense1f(
    const __half* __restrict__ hD, const int* __restrict__ list,
    const int* __restrict__ start, const int* __restrict__ hist,
    const __half* __restrict__ D1H, const float* __restrict__ d1b,
    const float* __restrict__ g3, const float* __restrict__ b3,
    const float* __restrict__ m3, const float* __restrict__ v3,
    float* __restrict__ g) {
  int b = blockIdx.x, tid = threadIdx.x;
  int lane = tid & 63, w = tid >> 6;
  int ln = lane & 15, q = lane >> 4;
  int stt = start[b], cnt = hist[b];

  float bj[2], sc[2], sh[2];
  #pragma unroll
  for (int nf = 0; nf < 2; nf++) {
    int col = w * 32 + nf * 16 + ln;
    bj[nf] = d1b[col];
    sc[nf] = g3[col] * rsqrtf(v3[col] + 1e-3f);
    sh[nf] = b3[col] - m3[col] * sc[nf];
  }

  float sum[2] = {0.f, 0.f};
  float mx[2] = {-INFINITY, -INFINITY};

  for (int cb = 0; cb < cnt; cb += 64) {
    int nr = min(64, cnt - cb);
    // this lane's 4 A rows (mf*16+ln), tail-clamped to a valid index
    int ridx[4];
    #pragma unroll
    for (int mf = 0; mf < 4; mf++) {
      int row = mf * 16 + ln;
      ridx[mf] = list[stt + cb + min(row, nr - 1)];
    }

    f32x4 acc[4][2];
    #pragma unroll
    for (int mf = 0; mf < 4; mf++)
      #pragma unroll
      for (int nf = 0; nf < 2; nf++) acc[mf][nf] = (f32x4){bj[nf], bj[nf], bj[nf], bj[nf]};

    #pragma unroll
    for (int hl = 1; hl >= 0; hl--) {
      #pragma unroll
      for (int ks = 0; ks < 2; ks++) {
        f16x8 af[4];
        #pragma unroll
        for (int mf = 0; mf < 4; mf++)
          af[mf] = *(const f16x8*)(hD + (size_t)ridx[mf] * 64 + ks * 32 + q * 8);
        #pragma unroll
        for (int nf = 0; nf < 2; nf++) {
          f16x8 bf = *(const f16x8*)(D1H + hl * 8192 +
                                     (w * 32 + nf * 16 + ln) * 64 + ks * 32 + q * 8);
          #pragma unroll
          for (int mf = 0; mf < 4; mf++)
            acc[mf][nf] = __builtin_amdgcn_mfma_f32_16x16x32_f16(af[mf], bf, acc[mf][nf], 0, 0, 0);
        }
      }
    }

    #pragma unroll
    for (int mf = 0; mf < 4; mf++) {
      #pragma unroll
      for (int nf = 0; nf < 2; nf++) {
        #pragma unroll
        for (int r = 0; r < 4; r++) {
          int row = mf * 16 + q * 4 + r;
          if (row < nr) {
            float v = tanh_fast(acc[mf][nf][r]) * sc[nf] + sh[nf];
            sum[nf] += v;
            mx[nf] = fmaxf(mx[nf], v);
          }
        }
      }
    }
  }

  #pragma unroll
  for (int nf = 0; nf < 2; nf++) {
    sum[nf] += __shfl_xor(sum[nf], 16);
    sum[nf] += __shfl_xor(sum[nf], 32);
    mx[nf] = fmaxf(mx[nf], __shfl_xor(mx[nf], 16));
    mx[nf] = fmaxf(mx[nf], __shfl_xor(mx[nf], 32));
  }
  if (q == 0) {
    #pragma unroll
    for (int nf = 0; nf < 2; nf++) {
      int col = w * 32 + nf * 16 + ln;
      g[b * 256 + col] = tanh_fast(sum[nf]);
      g[b * 256 + 128 + col] = tanh_fast(mx[nf]);
    }
  }
}

// ---------------- dense2 -> sigmoid -> dense3 ----------------
__global__ __launch_bounds__(64) void k_dense23(
    const float* __restrict__ g, const float* __restrict__ W2,
    const float* __restrict__ b2, const float* __restrict__ W3,
    const float* __restrict__ b3, float* __restrict__ out) {
  __shared__ float gr[256];
  int b = blockIdx.x, j = threadIdx.x;
  ((float4*)gr)[j] = ((const float4*)(g + b * 256))[j];
  __syncthreads();
  float acc = b2[j];
  #pragma unroll 8
  for (int k = 0; k < 256; k++) acc += gr[k] * W2[k * 64 + j];
  float sg = 1.f / (1.f + expf(-acc));
  float p = sg * W3[j];
  #pragma unroll
  for (int off = 32; off >= 1; off >>= 1) p += __shfl_xor(p, off);
  if (j == 0) out[b] = p + b3[0];
}

// ---------------- launch ----------------
extern "C" void kernel_launch(void* const* d_in, const int* in_sizes, int n_in,
                              void* d_out, int out_size, void* d_ws, size_t ws_size,
                              hipStream_t stream) {
  const float* feat = (const float*)d_in[0];
  const int*   mem  = (const int*)d_in[1];
  AdjPtrs adjs;
  for (int i = 0; i < 6; i++) adjs.p[i] = (const int*)d_in[2 + i];
  const float* gc1_Wn = (const float*)d_in[8];
  const float* gc1_Ws = (const float*)d_in[9];
  const float* gc1_b  = (const float*)d_in[10];
  const float* gc2_Wn = (const float*)d_in[11];
  const float* gc2_Ws = (const float*)d_in[12];
  const float* gc2_b  = (const float*)d_in[13];
  const float* bn1g = (const float*)d_in[14];
  const float* bn1b = (const float*)d_in[15];
  const float* bn1m = (const float*)d_in[16];
  const float* bn1v = (const float*)d_in[17];
  const float* bn3g = (const float*)d_in[18];
  const float* bn3b = (const float*)d_in[19];
  const float* bn3m = (const float*)d_in[20];
  const float* bn3v = (const float*)d_in[21];
  const float* d1W = (const float*)d_in[22];
  const float* d1b = (const float*)d_in[23];
  const float* d2W = (const float*)d_in[24];
  const float* d2b = (const float*)d_in[25];
  const float* d3W = (const float*)d_in[26];
  const float* d3b = (const float*)d_in[27];
  float* out = (float*)d_out;

  char* w = (char*)d_ws;
  __half* featH = (__half*)(w);
  __half* hA    = (__half*)(w + 80000000LL);
  __half* hB    = (__half*)(w + 144000000LL);
  __half* hC    = (__half*)(w);              // gc2 out (featH dead)
  __half* hD    = (__half*)(w + 80000000LL); // pool2 out (hA dead)
  __half* W1H   = (__half*)(w + 210000000LL);
  __half* W2H   = (__half*)(w + 210200000LL);
  __half* D1H   = (__half*)(w + 210330000LL);  // 32 KB hi/lo
  float*  g     = (float*)(w + 210400000LL);   // 1 MB
  int* hist     = (int*)(w + 211600000LL);
  int* start    = (int*)(w + 211604096LL);
  int* list     = (int*)(w + 211612288LL);     // 2 MB
  // hist2 (2 MB) aliases hB: sort completes (stream-serial) before pool1 writes hB
  int* hist2    = (int*)(w + 144000000LL);

  // membership counting sort (no global atomics)
  k_hist_blk<<<SORT_NB, 256, 0, stream>>>(mem, hist2);
  k_scan_blk<<<1024, SORT_NB, 0, stream>>>(hist2, hist);
  k_scan<<<1, 1024, 0, stream>>>(hist, start);
  k_scatter_blk<<<SORT_NB, 256, 0, stream>>>(mem, start, hist2, list);

  // prep
  k_prep<<<78125, 256, 0, stream>>>(feat, (__half2*)featH);
  k_prep_w<<<504, 256, 0, stream>>>(gc1_Ws, gc1_Wn, gc2_Ws, gc2_Wn, W1H, W2H);
  k_prep_d1<<<32, 256, 0, stream>>>(d1W, D1H);

  // main pipeline
  k_gcm<80, 5><<<7815, 256, 0, stream>>>(featH, adjs, W1H, gc1_b,
                                         bn1g, bn1b, bn1m, bn1v, hA);
  k_pool_h<<<15625, 256, 0, stream>>>((const f16x8*)hA, adjs, (f16x8*)hB);
  k_gcm<64, 4><<<7815, 256, 0, stream>>>(hB, adjs, W2H, gc2_b,
                                         bn1g, bn1b, bn1m, bn1v, hC);
  k_pool_h<<<15625, 256, 0, stream>>>((const f16x8*)hC, adjs, (f16x8*)hD);
  k_dense1f<<<1024, 256, 0, stream>>>((const __half*)hD, list, start, hist, D1H, d1b,
                                      bn3g, bn3b, bn3m, bn3v, g);
  k_dense23<<<1024, 64, 0, stream>>>(g, d2W, d2b, d3W, d3b, out);
}